// Round 17
// baseline (40.432 us; speedup 1.0000x reference)
//
#include <hip/hip_runtime.h>
#include <math.h>

#define TLEN 1048576
#define MAXLEN 1992296
#define CCH 2
#define BLK 64    // threads per block (1 wave): barriers are no-ops, LDS/block ~6KB

// ---- all 8 batches' filter banks in one kernarg struct (scalar s_load path) ----
#define NC_TOTAL 5070
struct AllK { float c[NC_TOTAL]; };

// per-batch coefficient offsets inside AllK::c
#define KOFF0 0      // N=4,  L=21  -> 84
#define KOFF1 84     // N=23, L=54  -> 1242
#define KOFF2 1326   // N=1,  L=15  -> 15
#define KOFF3 1341   // N=9,  L=27  -> 243
#define KOFF4 1584   // N=21, L=54  -> 1134
#define KOFF5 2718   // N=17, L=56  -> 952
#define KOFF6 3670   // N=11, L=34  -> 374
#define KOFF7 4044   // N=19, L=54  -> 1026

// OVERLAY LDS (outputs reuse input region). SHMAX at BLK=64 = b1 BOUTP = 1519
// floats = 6.1 KB -> ~26 resident blocks/CU (~26 waves) from ~26 consecutive
// pattern positions = deep cross-batch phase mixing.
#define SHMAX 1519

// Polyphase resample — R16 body at BLK=64 (1 wave: __syncthreads ~ free).
template<int O, int N, int W, int FPT, bool FLIP, int TGT, int KOFF>
__device__ __forceinline__ void resample_block(
    const float* __restrict__ x,   // this batch: (C, TLEN)
    float* __restrict__ out,       // this batch: (C, MAXLEN)
    const AllK& K, int bl, float* sh)
{
  constexpr int L    = 2*W + O;
  constexpr int WSZ  = (FPT-1)*O + L;
  constexpr int OPT  = FPT*N;
  constexpr int BF   = BLK*FPT;
  constexpr int GSZ  = (BF-1)*O + L;
  constexpr int BOUT = BLK*OPT;

  const int tid = threadIdx.x;
  const int c   = bl & 1;
  const int f0  = (bl >> 1) * BF;
  const float* __restrict__ xc = x + (size_t)c * TLEN;
  float* __restrict__ oc = out + (size_t)c * MAXLEN;

  // ---- stage input tile to LDS: float4 loads, skewed writes ----
  const int g0  = f0 * O - W;
  const int g0a = g0 & ~3;            // floor to 4-elem alignment (works for g0<0)
  const int d   = g0 - g0a;           // 0..3
  for (int u = tid * 4; u < GSZ + d; u += BLK*4) {
    int g = g0a + u;
    float v0, v1, v2, v3;
    if (g >= 0 && g + 3 < TLEN) {
      float4 v = *reinterpret_cast<const float4*>(xc + g);
      v0 = v.x; v1 = v.y; v2 = v.z; v3 = v.w;
    } else {
      v0 = (g   >= 0 && g   < TLEN) ? xc[g]   : 0.0f;
      v1 = (g+1 >= 0 && g+1 < TLEN) ? xc[g+1] : 0.0f;
      v2 = (g+2 >= 0 && g+2 < TLEN) ? xc[g+2] : 0.0f;
      v3 = (g+3 >= 0 && g+3 < TLEN) ? xc[g+3] : 0.0f;
    }
    int s0 = u - d;
    if (s0   >= 0 && s0   < GSZ) sh[s0   + (s0  >>5)] = v0;
    if (s0+1 >= 0 && s0+1 < GSZ) sh[s0+1 + ((s0+1)>>5)] = v1;
    if (s0+2 >= 0 && s0+2 < GSZ) sh[s0+2 + ((s0+2)>>5)] = v2;
    if (s0+3 >= 0 && s0+3 < GSZ) sh[s0+3 + ((s0+3)>>5)] = v3;
  }
  __syncthreads();

  // ---- window to registers (static indices; stays in VGPRs) ----
  float win[WSZ];
  {
    const int base = tid * (FPT * O);
    #pragma unroll
    for (int l = 0; l < WSZ; ++l) {
      int idx = base + l;
      win[l] = sh[idx + (idx >> 5)];
    }
  }
  __syncthreads();  // all reads of the input tile done; region reused for outputs

  // ---- RUNTIME phase loop: L FMAs of code, executed N times -> LDS (skewed) ----
  #pragma unroll 1
  for (int j = 0; j < N; ++j) {
    const int kb = KOFF + j * L;     // uniform -> scalar loads
    #pragma unroll
    for (int p = 0; p < FPT; ++p) {
      float acc = 0.0f;
      #pragma unroll
      for (int l = 0; l < L; ++l)
        acc = fmaf(K.c[kb + l], win[p*O + l], acc);
      int oi = tid * OPT + p * N + j;
      sh[oi + (oi >> 5)] = acc;
    }
  }
  __syncthreads();

  // ---- coalesced dump (+ mirrored copy for flip batches) ----
  const int m0 = f0 * N;
  #pragma unroll
  for (int r = 0; r < BOUT/BLK; ++r) {
    int q = r*BLK + tid;
    int m = m0 + q;
    if (m < TGT) {
      float v = sh[q + (q >> 5)];
      oc[m] = v;
      if (FLIP) oc[2*TGT - 1 - m] = v;
    }
  }
}

// ---- PROPORTIONAL 25-SLOT INTERLEAVE (BLK=64) ----
// Block counts (both channels): b0 3278, b1 1640, b2 4096, b3 3278, b4 1640,
// b5 1640, b6 3278, b7 1640 (total 20490). Multiplicities per 25-slot group:
// {4,2,5,4,2,2,4,2} x 820 groups = 20500 slots (10 wasted, guarded).
// 25 coprime with 256 -> co-resident blocks on a CU span different pattern
// positions AND generations -> deep batch/phase mixing (fixes R13 confound).
#define NRES 20500        // 25 * 820
#define NPADB 2004
#define NBLK (NRES + NPADB) // 22504

__global__ __launch_bounds__(BLK) void fused_kernel(
    const float* __restrict__ x, float* __restrict__ out, AllK K)
{
  __shared__ float sh[SHMAX];
  const int b = (int)blockIdx.x;

  if (b < NRES) {
    constexpr int PBAT[25] = {2,0,3,6,1,2,4,0,5,3,7,2,6,0,1,3,2,4,6,0,5,2,7,3,6};
    constexpr int PRNK[25] = {0,0,0,0,0,1,0,1,0,1,0,2,1,2,1,2,3,1,2,3,1,4,1,3,3};
    constexpr int MULT[8]  = {4,2,5,4,2,2,4,2};
    const int g = b / 25;
    const int p = b - g * 25;
    const int i = PBAT[p];
    const int idx = g * MULT[i] + PRNK[p];
    if (i == 0) {
      if (idx < 3278) resample_block< 5,  4, 8, 2, true,   838861, KOFF0>(x + 0*CCH*(size_t)TLEN, out + 0*CCH*(size_t)MAXLEN, K, idx, sh);
    } else if (i == 1) {
      if (idx < 1640) resample_block<20, 23, 7, 1, false, 1205863, KOFF1>(x + 1*CCH*(size_t)TLEN, out + 1*CCH*(size_t)MAXLEN, K, idx, sh);
    } else if (i == 2) {
      if (idx < 4096) resample_block< 1,  1, 7, 8, false, 1048576, KOFF2>(x + 2*CCH*(size_t)TLEN, out + 2*CCH*(size_t)MAXLEN, K, idx, sh);
    } else if (i == 3) {
      if (idx < 3278) resample_block<10,  9, 7, 1, true,   943719, KOFF3>(x + 3*CCH*(size_t)TLEN, out + 3*CCH*(size_t)MAXLEN, K, idx, sh);
    } else if (i == 4) {
      if (idx < 1640) resample_block<20, 21, 7, 1, false, 1101005, KOFF4>(x + 4*CCH*(size_t)TLEN, out + 4*CCH*(size_t)MAXLEN, K, idx, sh);
    } else if (i == 5) {
      if (idx < 1640) resample_block<20, 17, 8, 1, true,   891290, KOFF5>(x + 5*CCH*(size_t)TLEN, out + 5*CCH*(size_t)MAXLEN, K, idx, sh);
    } else if (i == 6) {
      if (idx < 3278) resample_block<10, 11, 7, 1, false, 1153434, KOFF6>(x + 6*CCH*(size_t)TLEN, out + 6*CCH*(size_t)MAXLEN, K, idx, sh);
    } else {
      if (idx < 1640) resample_block<20, 19, 7, 1, true,   996148, KOFF7>(x + 7*CCH*(size_t)TLEN, out + 7*CCH*(size_t)MAXLEN, K, idx, sh);
    }
  } else {
    // ---- zero-fill padding [len_i, MAXLEN), vectorized; 4096 elems per block ----
    const int pb = b - NRES;
    constexpr int PSTART[14] = {0,77,154,347,540,771,1002,1028,1054,1272,1490,1542,1594,1799};
    constexpr int LEN[7]     = {1677722,1205863,1048576,1887438,1101005,1782580,1153434};
    int row = 0;
    #pragma unroll
    for (int r = 1; r < 14; ++r) if (pb >= PSTART[r]) row = r;
    const int i   = row >> 1;
    const int len = LEN[i];
    const int A   = (len + 3) & ~3;          // first 16B-aligned pad element
    float* __restrict__ orow = out + (size_t)row * MAXLEN;  // row == i*2+c
    if (pb == PSTART[row] && (int)threadIdx.x < A - len)
      orow[len + (int)threadIdx.x] = 0.0f;   // 0..3 head scalars
    const int base = A + (pb - PSTART[row]) * 4096;
    const float4 z = make_float4(0.f, 0.f, 0.f, 0.f);
    #pragma unroll
    for (int e = 0; e < 16; ++e) {
      int m = base + (e*BLK + (int)threadIdx.x) * 4;
      if (m + 3 < MAXLEN) *reinterpret_cast<float4*>(orow + m) = z;
    }
  }
}

// Host-side faithful port of torchaudio's sinc kernel (double precision).
template<int O, int N, int W>
static void fill_coef(float* c) {
  constexpr int L = 2*W + O;
  const double base = (double)(O < N ? O : N) * 0.99;
  for (int j = 0; j < N; ++j) {
    for (int l = 0; l < L; ++l) {
      double t = (-(double)j / (double)N + (double)(l - W) / (double)O) * base;
      if (t < -6.0) t = -6.0;
      if (t >  6.0) t =  6.0;
      double w = cos(t * M_PI / 12.0); w = w * w;
      double tp = t * M_PI;
      double s = (t == 0.0) ? 1.0 : sin(tp) / tp;
      c[j*L + l] = (float)(s * w * base / (double)O);
    }
  }
}

extern "C" void kernel_launch(void* const* d_in, const int* in_sizes, int n_in,
                              void* d_out, int out_size, void* d_ws, size_t ws_size,
                              hipStream_t stream) {
  (void)in_sizes; (void)n_in; (void)out_size; (void)d_ws; (void)ws_size;
  const float* x = (const float*)d_in[0];
  float* out = (float*)d_out;

  AllK K;
  fill_coef< 5,  4, 8>(K.c + KOFF0);
  fill_coef<20, 23, 7>(K.c + KOFF1);
  fill_coef< 1,  1, 7>(K.c + KOFF2);
  fill_coef<10,  9, 7>(K.c + KOFF3);
  fill_coef<20, 21, 7>(K.c + KOFF4);
  fill_coef<20, 17, 8>(K.c + KOFF5);
  fill_coef<10, 11, 7>(K.c + KOFF6);
  fill_coef<20, 19, 7>(K.c + KOFF7);

  hipLaunchKernelGGL(fused_kernel, dim3(NBLK), dim3(BLK), 0, stream, x, out, K);
}

// Round 18
// 38.998 us; speedup vs baseline: 1.0368x; 1.0368x over previous
//
#include <hip/hip_runtime.h>
#include <math.h>

#define TLEN 1048576
#define MAXLEN 1992296
#define CCH 2
#define BLK 128   // threads per block (2 waves)

// ---- all 8 batches' filter banks in one kernarg struct (scalar s_load path) ----
#define NC_TOTAL 5070
struct AllK { float c[NC_TOTAL]; };

// per-batch coefficient offsets inside AllK::c
#define KOFF0 0      // N=4,  L=21  -> 84
#define KOFF1 84     // N=23, L=54  -> 1242
#define KOFF2 1326   // N=1,  L=15  -> 15
#define KOFF3 1341   // N=9,  L=27  -> 243
#define KOFF4 1584   // N=21, L=54  -> 1134
#define KOFF5 2718   // N=17, L=56  -> 952
#define KOFF6 3670   // N=11, L=34  -> 374
#define KOFF7 4044   // N=19, L=54  -> 1026

// OVERLAY LDS (outputs reuse input region, 3-barrier). SHMAX = 3037 floats =
// 12.1 KB -> ~13 resident blocks/CU for deep cross-generation phase mixing.
#define SHMAX 3037

// Polyphase resample — R16 body (validated 38.5us).
template<int O, int N, int W, int FPT, bool FLIP, int TGT, int KOFF>
__device__ __forceinline__ void resample_block(
    const float* __restrict__ x,   // this batch: (C, TLEN)
    float* __restrict__ out,       // this batch: (C, MAXLEN)
    const AllK& K, int bl, float* sh)
{
  constexpr int L    = 2*W + O;
  constexpr int WSZ  = (FPT-1)*O + L;
  constexpr int OPT  = FPT*N;
  constexpr int BF   = BLK*FPT;
  constexpr int GSZ  = (BF-1)*O + L;
  constexpr int BOUT = BLK*OPT;

  const int tid = threadIdx.x;
  const int c   = bl & 1;
  const int f0  = (bl >> 1) * BF;
  const float* __restrict__ xc = x + (size_t)c * TLEN;
  float* __restrict__ oc = out + (size_t)c * MAXLEN;

  // ---- stage input tile to LDS: float4 loads, skewed writes ----
  const int g0  = f0 * O - W;
  const int g0a = g0 & ~3;            // floor to 4-elem alignment (works for g0<0)
  const int d   = g0 - g0a;           // 0..3
  for (int u = tid * 4; u < GSZ + d; u += BLK*4) {
    int g = g0a + u;
    float v0, v1, v2, v3;
    if (g >= 0 && g + 3 < TLEN) {
      float4 v = *reinterpret_cast<const float4*>(xc + g);
      v0 = v.x; v1 = v.y; v2 = v.z; v3 = v.w;
    } else {
      v0 = (g   >= 0 && g   < TLEN) ? xc[g]   : 0.0f;
      v1 = (g+1 >= 0 && g+1 < TLEN) ? xc[g+1] : 0.0f;
      v2 = (g+2 >= 0 && g+2 < TLEN) ? xc[g+2] : 0.0f;
      v3 = (g+3 >= 0 && g+3 < TLEN) ? xc[g+3] : 0.0f;
    }
    int s0 = u - d;
    if (s0   >= 0 && s0   < GSZ) sh[s0   + (s0  >>5)] = v0;
    if (s0+1 >= 0 && s0+1 < GSZ) sh[s0+1 + ((s0+1)>>5)] = v1;
    if (s0+2 >= 0 && s0+2 < GSZ) sh[s0+2 + ((s0+2)>>5)] = v2;
    if (s0+3 >= 0 && s0+3 < GSZ) sh[s0+3 + ((s0+3)>>5)] = v3;
  }
  __syncthreads();

  // ---- window to registers (static indices; stays in VGPRs) ----
  float win[WSZ];
  {
    const int base = tid * (FPT * O);
    #pragma unroll
    for (int l = 0; l < WSZ; ++l) {
      int idx = base + l;
      win[l] = sh[idx + (idx >> 5)];
    }
  }
  __syncthreads();  // all reads of the input tile done; region reused for outputs

  // ---- RUNTIME phase loop: L FMAs of code, executed N times -> LDS (skewed) ----
  #pragma unroll 1
  for (int j = 0; j < N; ++j) {
    const int kb = KOFF + j * L;     // uniform -> scalar loads
    #pragma unroll
    for (int p = 0; p < FPT; ++p) {
      float acc = 0.0f;
      #pragma unroll
      for (int l = 0; l < L; ++l)
        acc = fmaf(K.c[kb + l], win[p*O + l], acc);
      int oi = tid * OPT + p * N + j;
      sh[oi + (oi >> 5)] = acc;
    }
  }
  __syncthreads();

  // ---- coalesced dump (+ mirrored copy for flip batches) ----
  const int m0 = f0 * N;
  #pragma unroll
  for (int r = 0; r < BOUT/BLK; ++r) {
    int q = r*BLK + tid;
    int m = m0 + q;
    if (m < TGT) {
      float v = sh[q + (q >> 5)];
      oc[m] = v;
      if (FLIP) oc[2*TGT - 1 - m] = v;
    }
  }
}

// ---- GENERATION-INTERLEAVED MAPPING (R15/R16, validated) ----
// batch = (b>>8)&7; tile = ((b>>11)<<8)|(b&255).
// NEW: wasted slots (idx >= count) now carry the pad-fill work instead of a
// tail cohort -> pad stores spread across the whole run, grid tail deleted.
#define NRES (64*256)     // 16384 = whole grid now
#define NPADB 2004

__global__ __launch_bounds__(BLK) void fused_kernel(
    const float* __restrict__ x, float* __restrict__ out, AllK K)
{
  __shared__ float sh[SHMAX];
  const int b = (int)blockIdx.x;

  const int i   = (b >> 8) & 7;                    // batch = generation % 8
  const int idx = ((b >> 11) << 8) | (b & 255);    // tile within batch
  constexpr int CNT[8] = {1640, 820, 2048, 1640, 820, 820, 1640, 820};
  constexpr int WCU[8] = {0, 408, 1636, 1636, 2044, 3272, 4500, 4908}; // cum. wasted

  if (idx < CNT[i]) {
    if (i == 0) {
      resample_block< 5,  4, 8, 2, true,   838861, KOFF0>(x + 0*CCH*(size_t)TLEN, out + 0*CCH*(size_t)MAXLEN, K, idx, sh);
    } else if (i == 1) {
      resample_block<20, 23, 7, 1, false, 1205863, KOFF1>(x + 1*CCH*(size_t)TLEN, out + 1*CCH*(size_t)MAXLEN, K, idx, sh);
    } else if (i == 2) {
      resample_block< 1,  1, 7, 8, false, 1048576, KOFF2>(x + 2*CCH*(size_t)TLEN, out + 2*CCH*(size_t)MAXLEN, K, idx, sh);
    } else if (i == 3) {
      resample_block<10,  9, 7, 1, true,   943719, KOFF3>(x + 3*CCH*(size_t)TLEN, out + 3*CCH*(size_t)MAXLEN, K, idx, sh);
    } else if (i == 4) {
      resample_block<20, 21, 7, 1, false, 1101005, KOFF4>(x + 4*CCH*(size_t)TLEN, out + 4*CCH*(size_t)MAXLEN, K, idx, sh);
    } else if (i == 5) {
      resample_block<20, 17, 8, 1, true,   891290, KOFF5>(x + 5*CCH*(size_t)TLEN, out + 5*CCH*(size_t)MAXLEN, K, idx, sh);
    } else if (i == 6) {
      resample_block<10, 11, 7, 1, false, 1153434, KOFF6>(x + 6*CCH*(size_t)TLEN, out + 6*CCH*(size_t)MAXLEN, K, idx, sh);
    } else {
      resample_block<20, 19, 7, 1, true,   996148, KOFF7>(x + 7*CCH*(size_t)TLEN, out + 7*CCH*(size_t)MAXLEN, K, idx, sh);
    }
  } else {
    // ---- pad-fill routed through wasted slots: pad_id = WCU[i] + idx-CNT[i] ----
    const int pb = WCU[i] + (idx - CNT[i]);
    if (pb < NPADB) {
      constexpr int PSTART[14] = {0,77,154,347,540,771,1002,1028,1054,1272,1490,1542,1594,1799};
      constexpr int LEN[7]     = {1677722,1205863,1048576,1887438,1101005,1782580,1153434};
      int row = 0;
      #pragma unroll
      for (int r = 1; r < 14; ++r) if (pb >= PSTART[r]) row = r;
      const int bi  = row >> 1;
      const int len = LEN[bi];
      const int A   = (len + 3) & ~3;          // first 16B-aligned pad element
      float* __restrict__ orow = out + (size_t)row * MAXLEN;  // row == bi*2+c
      if (pb == PSTART[row] && (int)threadIdx.x < A - len)
        orow[len + (int)threadIdx.x] = 0.0f;   // 0..3 head scalars
      const int base = A + (pb - PSTART[row]) * 4096;
      const float4 z = make_float4(0.f, 0.f, 0.f, 0.f);
      #pragma unroll
      for (int e = 0; e < 8; ++e) {
        int m = base + (e*BLK + (int)threadIdx.x) * 4;
        if (m + 3 < MAXLEN) *reinterpret_cast<float4*>(orow + m) = z;
      }
    }
  }
}

// Host-side faithful port of torchaudio's sinc kernel (double precision).
template<int O, int N, int W>
static void fill_coef(float* c) {
  constexpr int L = 2*W + O;
  const double base = (double)(O < N ? O : N) * 0.99;
  for (int j = 0; j < N; ++j) {
    for (int l = 0; l < L; ++l) {
      double t = (-(double)j / (double)N + (double)(l - W) / (double)O) * base;
      if (t < -6.0) t = -6.0;
      if (t >  6.0) t =  6.0;
      double w = cos(t * M_PI / 12.0); w = w * w;
      double tp = t * M_PI;
      double s = (t == 0.0) ? 1.0 : sin(tp) / tp;
      c[j*L + l] = (float)(s * w * base / (double)O);
    }
  }
}

extern "C" void kernel_launch(void* const* d_in, const int* in_sizes, int n_in,
                              void* d_out, int out_size, void* d_ws, size_t ws_size,
                              hipStream_t stream) {
  (void)in_sizes; (void)n_in; (void)out_size; (void)d_ws; (void)ws_size;
  const float* x = (const float*)d_in[0];
  float* out = (float*)d_out;

  AllK K;
  fill_coef< 5,  4, 8>(K.c + KOFF0);
  fill_coef<20, 23, 7>(K.c + KOFF1);
  fill_coef< 1,  1, 7>(K.c + KOFF2);
  fill_coef<10,  9, 7>(K.c + KOFF3);
  fill_coef<20, 21, 7>(K.c + KOFF4);
  fill_coef<20, 17, 8>(K.c + KOFF5);
  fill_coef<10, 11, 7>(K.c + KOFF6);
  fill_coef<20, 19, 7>(K.c + KOFF7);

  hipLaunchKernelGGL(fused_kernel, dim3(NRES), dim3(BLK), 0, stream, x, out, K);
}

// Round 19
// 38.122 us; speedup vs baseline: 1.0606x; 1.0230x over previous
//
#include <hip/hip_runtime.h>
#include <math.h>

#define TLEN 1048576
#define MAXLEN 1992296
#define CCH 2
#define BLK 128   // threads per block (2 waves)

// ---- all 8 batches' filter banks in one kernarg struct (scalar s_load path) ----
#define NC_TOTAL 5070
struct AllK { float c[NC_TOTAL]; };

// per-batch coefficient offsets inside AllK::c
#define KOFF0 0      // N=4,  L=21  -> 84
#define KOFF1 84     // N=23, L=54  -> 1242
#define KOFF2 1326   // N=1,  L=15  -> 15
#define KOFF3 1341   // N=9,  L=27  -> 243
#define KOFF4 1584   // N=21, L=54  -> 1134
#define KOFF5 2718   // N=17, L=56  -> 952
#define KOFF6 3670   // N=11, L=34  -> 374
#define KOFF7 4044   // N=19, L=54  -> 1026

// OVERLAY LDS (outputs reuse input region, 3-barrier). SHMAX = 3037 floats
// covers: skewed GSZP (inputs), skewed BOUTP (b0/b2 outputs), unskewed BOUT
// (odd-OPT outputs, max b1 = 2944).
#define SHMAX 3037

// Polyphase resample — R16 body; odd-OPT batches use an UNSKEWED output region
// (odd stride mod 32 banks is conflict-free) enabling float4 LDS reads and
// float4/float2 vector stores in the dump. b0/b2 (OPT=8) keep the skewed
// scalar path (unskewed OPT=8 would be a 16-way bank conflict).
template<int O, int N, int W, int FPT, bool FLIP, int TGT, int KOFF>
__device__ __forceinline__ void resample_block(
    const float* __restrict__ x,   // this batch: (C, TLEN)
    float* __restrict__ out,       // this batch: (C, MAXLEN)
    const AllK& K, int bl, float* sh)
{
  constexpr int L    = 2*W + O;
  constexpr int WSZ  = (FPT-1)*O + L;
  constexpr int OPT  = FPT*N;
  constexpr int BF   = BLK*FPT;
  constexpr int GSZ  = (BF-1)*O + L;
  constexpr int BOUT = BLK*OPT;
  constexpr bool VEC = (OPT % 2) == 1;   // odd stride -> no skew needed

  const int tid = threadIdx.x;
  const int c   = bl & 1;
  const int f0  = (bl >> 1) * BF;
  const float* __restrict__ xc = x + (size_t)c * TLEN;
  float* __restrict__ oc = out + (size_t)c * MAXLEN;

  // ---- stage input tile to LDS: float4 loads, skewed writes ----
  const int g0  = f0 * O - W;
  const int g0a = g0 & ~3;            // floor to 4-elem alignment (works for g0<0)
  const int d   = g0 - g0a;           // 0..3
  for (int u = tid * 4; u < GSZ + d; u += BLK*4) {
    int g = g0a + u;
    float v0, v1, v2, v3;
    if (g >= 0 && g + 3 < TLEN) {
      float4 v = *reinterpret_cast<const float4*>(xc + g);
      v0 = v.x; v1 = v.y; v2 = v.z; v3 = v.w;
    } else {
      v0 = (g   >= 0 && g   < TLEN) ? xc[g]   : 0.0f;
      v1 = (g+1 >= 0 && g+1 < TLEN) ? xc[g+1] : 0.0f;
      v2 = (g+2 >= 0 && g+2 < TLEN) ? xc[g+2] : 0.0f;
      v3 = (g+3 >= 0 && g+3 < TLEN) ? xc[g+3] : 0.0f;
    }
    int s0 = u - d;
    if (s0   >= 0 && s0   < GSZ) sh[s0   + (s0  >>5)] = v0;
    if (s0+1 >= 0 && s0+1 < GSZ) sh[s0+1 + ((s0+1)>>5)] = v1;
    if (s0+2 >= 0 && s0+2 < GSZ) sh[s0+2 + ((s0+2)>>5)] = v2;
    if (s0+3 >= 0 && s0+3 < GSZ) sh[s0+3 + ((s0+3)>>5)] = v3;
  }
  __syncthreads();

  // ---- window to registers (static indices; stays in VGPRs) ----
  float win[WSZ];
  {
    const int base = tid * (FPT * O);
    #pragma unroll
    for (int l = 0; l < WSZ; ++l) {
      int idx = base + l;
      win[l] = sh[idx + (idx >> 5)];
    }
  }
  __syncthreads();  // all reads of the input tile done; region reused for outputs

  // ---- RUNTIME phase loop: L FMAs of code, executed N times -> LDS ----
  #pragma unroll 1
  for (int j = 0; j < N; ++j) {
    const int kb = KOFF + j * L;     // uniform -> scalar loads
    #pragma unroll
    for (int p = 0; p < FPT; ++p) {
      float acc = 0.0f;
      #pragma unroll
      for (int l = 0; l < L; ++l)
        acc = fmaf(K.c[kb + l], win[p*O + l], acc);
      int oi = tid * OPT + p * N + j;
      if constexpr (VEC) sh[oi] = acc;          // odd stride: conflict-free
      else               sh[oi + (oi >> 5)] = acc;
    }
  }
  __syncthreads();

  // ---- dump ----
  const int m0 = f0 * N;
  if constexpr (VEC) {
    // float4 LDS reads (contiguous, 2-way=free) + float4 stores; float2 mirror.
    constexpr int C4 = BOUT / 4;               // BLK=128 -> BOUT%4==0
    #pragma unroll
    for (int r = 0; r < (C4 + BLK - 1) / BLK; ++r) {
      int ch = r*BLK + tid;
      if (ch < C4) {
        int q4 = ch * 4;
        int m  = m0 + q4;
        float4 v = *reinterpret_cast<const float4*>(sh + q4);
        if (m + 3 < TGT) {
          *reinterpret_cast<float4*>(oc + m) = v;
          if (FLIP) {
            *reinterpret_cast<float2*>(oc + (2*TGT - 2 - m)) = make_float2(v.y, v.x);
            *reinterpret_cast<float2*>(oc + (2*TGT - 4 - m)) = make_float2(v.w, v.z);
          }
        } else {
          float vv[4] = {v.x, v.y, v.z, v.w};
          #pragma unroll
          for (int k = 0; k < 4; ++k) if (m + k < TGT) {
            oc[m + k] = vv[k];
            if (FLIP) oc[2*TGT - 1 - (m + k)] = vv[k];
          }
        }
      }
    }
  } else {
    #pragma unroll
    for (int r = 0; r < BOUT/BLK; ++r) {
      int q = r*BLK + tid;
      int m = m0 + q;
      if (m < TGT) {
        float v = sh[q + (q >> 5)];
        oc[m] = v;
        if (FLIP) oc[2*TGT - 1 - m] = v;
      }
    }
  }
}

// ---- GENERATION-INTERLEAVED MAPPING (R15/R16, validated 38.5us) ----
#define NRES (64*256)     // 16384
#define NPADB 2004
#define NBLK (NRES + NPADB) // 18388

__global__ __launch_bounds__(BLK) void fused_kernel(
    const float* __restrict__ x, float* __restrict__ out, AllK K)
{
  __shared__ alignas(16) float sh[SHMAX];
  const int b = (int)blockIdx.x;

  if (b < NRES) {
    const int i   = (b >> 8) & 7;                    // batch = generation % 8
    const int idx = ((b >> 11) << 8) | (b & 255);    // tile within batch
    if (i == 0) {
      if (idx < 1640) resample_block< 5,  4, 8, 2, true,   838861, KOFF0>(x + 0*CCH*(size_t)TLEN, out + 0*CCH*(size_t)MAXLEN, K, idx, sh);
    } else if (i == 1) {
      if (idx <  820) resample_block<20, 23, 7, 1, false, 1205863, KOFF1>(x + 1*CCH*(size_t)TLEN, out + 1*CCH*(size_t)MAXLEN, K, idx, sh);
    } else if (i == 2) {
      if (idx < 2048) resample_block< 1,  1, 7, 8, false, 1048576, KOFF2>(x + 2*CCH*(size_t)TLEN, out + 2*CCH*(size_t)MAXLEN, K, idx, sh);
    } else if (i == 3) {
      if (idx < 1640) resample_block<10,  9, 7, 1, true,   943719, KOFF3>(x + 3*CCH*(size_t)TLEN, out + 3*CCH*(size_t)MAXLEN, K, idx, sh);
    } else if (i == 4) {
      if (idx <  820) resample_block<20, 21, 7, 1, false, 1101005, KOFF4>(x + 4*CCH*(size_t)TLEN, out + 4*CCH*(size_t)MAXLEN, K, idx, sh);
    } else if (i == 5) {
      if (idx <  820) resample_block<20, 17, 8, 1, true,   891290, KOFF5>(x + 5*CCH*(size_t)TLEN, out + 5*CCH*(size_t)MAXLEN, K, idx, sh);
    } else if (i == 6) {
      if (idx < 1640) resample_block<10, 11, 7, 1, false, 1153434, KOFF6>(x + 6*CCH*(size_t)TLEN, out + 6*CCH*(size_t)MAXLEN, K, idx, sh);
    } else {
      if (idx <  820) resample_block<20, 19, 7, 1, true,   996148, KOFF7>(x + 7*CCH*(size_t)TLEN, out + 7*CCH*(size_t)MAXLEN, K, idx, sh);
    }
  } else {
    // ---- zero-fill padding [len_i, MAXLEN), vectorized; 4096 elems per block ----
    const int pb = b - NRES;
    constexpr int PSTART[14] = {0,77,154,347,540,771,1002,1028,1054,1272,1490,1542,1594,1799};
    constexpr int LEN[7]     = {1677722,1205863,1048576,1887438,1101005,1782580,1153434};
    int row = 0;
    #pragma unroll
    for (int r = 1; r < 14; ++r) if (pb >= PSTART[r]) row = r;
    const int i   = row >> 1;
    const int len = LEN[i];
    const int A   = (len + 3) & ~3;          // first 16B-aligned pad element
    float* __restrict__ orow = out + (size_t)row * MAXLEN;  // row == i*2+c
    if (pb == PSTART[row] && (int)threadIdx.x < A - len)
      orow[len + (int)threadIdx.x] = 0.0f;   // 0..3 head scalars
    const int base = A + (pb - PSTART[row]) * 4096;
    const float4 z = make_float4(0.f, 0.f, 0.f, 0.f);
    #pragma unroll
    for (int e = 0; e < 8; ++e) {
      int m = base + (e*BLK + (int)threadIdx.x) * 4;
      if (m + 3 < MAXLEN) *reinterpret_cast<float4*>(orow + m) = z;
    }
  }
}

// Host-side faithful port of torchaudio's sinc kernel (double precision).
template<int O, int N, int W>
static void fill_coef(float* c) {
  constexpr int L = 2*W + O;
  const double base = (double)(O < N ? O : N) * 0.99;
  for (int j = 0; j < N; ++j) {
    for (int l = 0; l < L; ++l) {
      double t = (-(double)j / (double)N + (double)(l - W) / (double)O) * base;
      if (t < -6.0) t = -6.0;
      if (t >  6.0) t =  6.0;
      double w = cos(t * M_PI / 12.0); w = w * w;
      double tp = t * M_PI;
      double s = (t == 0.0) ? 1.0 : sin(tp) / tp;
      c[j*L + l] = (float)(s * w * base / (double)O);
    }
  }
}

extern "C" void kernel_launch(void* const* d_in, const int* in_sizes, int n_in,
                              void* d_out, int out_size, void* d_ws, size_t ws_size,
                              hipStream_t stream) {
  (void)in_sizes; (void)n_in; (void)out_size; (void)d_ws; (void)ws_size;
  const float* x = (const float*)d_in[0];
  float* out = (float*)d_out;

  AllK K;
  fill_coef< 5,  4, 8>(K.c + KOFF0);
  fill_coef<20, 23, 7>(K.c + KOFF1);
  fill_coef< 1,  1, 7>(K.c + KOFF2);
  fill_coef<10,  9, 7>(K.c + KOFF3);
  fill_coef<20, 21, 7>(K.c + KOFF4);
  fill_coef<20, 17, 8>(K.c + KOFF5);
  fill_coef<10, 11, 7>(K.c + KOFF6);
  fill_coef<20, 19, 7>(K.c + KOFF7);

  hipLaunchKernelGGL(fused_kernel, dim3(NBLK), dim3(BLK), 0, stream, x, out, K);
}